// Round 7
// baseline (268.792 us; speedup 1.0000x reference)
//
#include <hip/hip_runtime.h>

#define D 512
#define D4 (D / 4)
#define MAXC 256
#define FEPS 1e-12f
#define FBIG 3.0e38f
#define DROWS 8
#define TI 32    // i-rows per k_pos block
#define TJ 128   // j-cols per k_pos pass
#define NIT 5    // i-tiles (covers class counts up to 160)

__device__ __forceinline__ float wave_rsum(float v) {
#pragma unroll
    for (int o = 32; o > 0; o >>= 1) v += __shfl_down(v, o);
    return v;
}

__device__ __forceinline__ float wave_rsum_all(float v) {
#pragma unroll
    for (int o = 32; o > 0; o >>= 1) v += __shfl_xor(v, o);
    return v;
}

__device__ __forceinline__ float dot4(const float4 a, const float4 b) {
    return a.x * b.x + a.y * b.y + a.z * b.z + a.w * b.w;
}

// top_k tie-break: higher value wins; equal values -> smaller global index wins
__device__ __forceinline__ bool better(float v1, int j1, float v2, int j2) {
    return (v1 > v2) || (v1 == v2 && (unsigned)j1 < (unsigned)j2);
}

__device__ __forceinline__ void ins3(float v, int j, float& t0, float& t1, float& t2,
                                     int& x0, int& x1, int& x2) {
    if (j < 0) return;
    if (better(v, j, t0, x0)) { t2 = t1; x2 = x1; t1 = t0; x1 = x0; t0 = v; x0 = j; }
    else if (better(v, j, t1, x1)) { t2 = t1; x2 = x1; t1 = v; x1 = j; }
    else if (better(v, j, t2, x2)) { t2 = v; x2 = j; }
}

// --- 1. row L2-normalize + a2[i] + fused class histogram ---
__global__ void k_normalize(const float* __restrict__ emb, const int* __restrict__ targets,
                            float* __restrict__ embn, float* __restrict__ a2,
                            int* __restrict__ ccount) {
    const int i = blockIdx.x;
    const int tid = threadIdx.x;  // 128 threads, float4 each
    __shared__ float red[2];
    const float4 x = ((const float4*)(emb + (size_t)i * D))[tid];
    float ss = x.x * x.x + x.y * x.y + x.z * x.z + x.w * x.w;
    ss = wave_rsum(ss);
    if ((tid & 63) == 0) red[tid >> 6] = ss;
    __syncthreads();
    const float tot = red[0] + red[1];
    const float inv = 1.0f / fmaxf(sqrtf(tot), FEPS);
    const float4 y = make_float4(x.x * inv, x.y * inv, x.z * inv, x.w * inv);
    ((float4*)(embn + (size_t)i * D))[tid] = y;
    float s2 = y.x * y.x + y.y * y.y + y.z * y.z + y.w * y.w;
    s2 = wave_rsum(s2);
    __syncthreads();
    if ((tid & 63) == 0) red[tid >> 6] = s2;
    __syncthreads();
    if (tid == 0) {
        a2[i] = red[0] + red[1];
        atomicAdd(&ccount[targets[i]], 1);
    }
}

// --- 2. per-class offset (in-block prefix reduce) + deterministic row lists ---
__global__ void k_build(const int* __restrict__ t, const int* __restrict__ ccount,
                        int* __restrict__ coff, int* __restrict__ clist, int n,
                        const int* __restrict__ ncls) {
    const int C = *ncls;
    const int c = blockIdx.x;  // grid = MAXC
    if (c >= C) return;
    __shared__ int pref[256];
    pref[threadIdx.x] = ((int)threadIdx.x < c) ? ccount[threadIdx.x] : 0;
    __syncthreads();
    for (int s = 128; s > 0; s >>= 1) {
        if (threadIdx.x < s) pref[threadIdx.x] += pref[threadIdx.x + s];
        __syncthreads();
    }
    int base = pref[0];
    if (threadIdx.x == 0) coff[c] = base;
    __shared__ int wtot[4];
    for (int start = 0; start < n; start += 256) {
        const int j = start + (int)threadIdx.x;
        const bool flag = (j < n) && (t[j] == c);
        const unsigned long long m = __ballot(flag);
        const int lane = threadIdx.x & 63;
        const int w = threadIdx.x >> 6;
        const int pre = __popcll(m & ((1ull << lane) - 1ull));
        if (lane == 0) wtot[w] = __popcll(m);
        __syncthreads();
        int woff = 0;
        for (int k = 0; k < w; ++k) woff += wtot[k];
        const int tot = wtot[0] + wtot[1] + wtot[2] + wtot[3];
        if (flag) clist[base + woff + pre] = j;
        base += tot;
        __syncthreads();
    }
}

// --- 3. class centers: grid (4 d-chunks x MAXC), 128 threads ---
__global__ void k_centers(const float* __restrict__ embn, const int* __restrict__ clist,
                          const int* __restrict__ coff, const int* __restrict__ ccount,
                          float* __restrict__ centers) {
    const int c = blockIdx.y;
    const int dchunk = blockIdx.x;      // 32 float4 slots each
    const int cnt = ccount[c];
    const int off = (cnt > 0) ? coff[c] : 0;
    const int tid = threadIdx.x;        // 128
    const int slot = tid & 31;
    const int rg = tid >> 5;            // 0..3
    float4 s = make_float4(0.f, 0.f, 0.f, 0.f);
    for (int mi = rg; mi < cnt; mi += 4) {
        const int j = clist[off + mi];
        const float4 e = ((const float4*)(embn + (size_t)j * D))[dchunk * 32 + slot];
        s.x += e.x; s.y += e.y; s.z += e.z; s.w += e.w;
    }
    __shared__ float4 part[4][32];
    part[rg][slot] = s;
    __syncthreads();
    if (rg == 0) {
        const float4 p0 = part[0][slot], p1 = part[1][slot], p2 = part[2][slot], p3 = part[3][slot];
        const float inv = 1.0f / fmaxf((float)cnt, 1e-6f);
        const float4 v = make_float4((p0.x + p1.x + p2.x + p3.x) * inv,
                                     (p0.y + p1.y + p2.y + p3.y) * inv,
                                     (p0.z + p1.z + p2.z + p3.z) * inv,
                                     (p0.w + p1.w + p2.w + p3.w) * inv);
        ((float4*)(centers + (size_t)c * D))[dchunk * 32 + slot] = v;
    }
}

// --- 4. d_neg_min: 8 rows per block, one thread per class (cc2 inline) ---
__global__ void k_dneg(const float* __restrict__ embn, const float* __restrict__ a2,
                       const int* __restrict__ t, const float* __restrict__ centers,
                       float* __restrict__ dneg, int n, const int* __restrict__ ncls) {
    const int C = *ncls;
    const int i0 = blockIdx.x * DROWS;
    __shared__ __align__(16) float lrow[DROWS][D];
    __shared__ float la2[DROWS];
    __shared__ int lt[DROWS];
    __shared__ float mins[DROWS][128];
#pragma unroll
    for (int r = 0; r < DROWS; ++r) {
        if (i0 + r < n)
            ((float4*)lrow[r])[threadIdx.x] =
                ((const float4*)(embn + (size_t)(i0 + r) * D))[threadIdx.x];
    }
    if (threadIdx.x < DROWS) {
        const int ii = i0 + (int)threadIdx.x;
        la2[threadIdx.x] = (ii < n) ? a2[ii] : 0.f;
        lt[threadIdx.x] = (ii < n) ? t[ii] : -1;
    }
    __syncthreads();
    const int c = threadIdx.x;
    float best[DROWS];
    if (c < C) {
        float acc[DROWS];
#pragma unroll
        for (int r = 0; r < DROWS; ++r) acc[r] = 0.f;
        float c2acc = 0.f;
        const float4* cp = (const float4*)(centers + (size_t)c * D);
        for (int k = 0; k < D4; ++k) {
            const float4 cv = cp[k];
            c2acc += dot4(cv, cv);
#pragma unroll
            for (int r = 0; r < DROWS; ++r) {
                const float4 ev = ((const float4*)lrow[r])[k];
                acc[r] += cv.x * ev.x + cv.y * ev.y + cv.z * ev.z + cv.w * ev.w;
            }
        }
#pragma unroll
        for (int r = 0; r < DROWS; ++r) {
            const float sq = la2[r] + c2acc - 2.f * acc[r];
            float dv = sqrtf(fmaxf(sq, FEPS));
            if (lt[r] == c) dv = FBIG;
            best[r] = dv;
        }
    } else {
#pragma unroll
        for (int r = 0; r < DROWS; ++r) best[r] = FBIG;
    }
#pragma unroll
    for (int r = 0; r < DROWS; ++r) mins[r][threadIdx.x] = best[r];
    __syncthreads();
    for (int s = 64; s > 0; s >>= 1) {
        if (threadIdx.x < s) {
#pragma unroll
            for (int r = 0; r < DROWS; ++r)
                mins[r][threadIdx.x] = fminf(mins[r][threadIdx.x], mins[r][threadIdx.x + s]);
        }
        __syncthreads();
    }
    if (threadIdx.x < DROWS && i0 + (int)threadIdx.x < n)
        dneg[i0 + threadIdx.x] = mins[threadIdx.x][0];
}

// --- 5. per-class Gram + top-3 hardest positives + d_pos ---
// grid (NIT i-tiles x class), 256 threads as 8(ty) x 32(tx), 4x4 register tile.
// Coalesced staging (lane groups of 8 read one row's 128B) + register prefetch
// pipeline (chunk t+1 loads in flight while chunk t computes).
__global__ __launch_bounds__(256) void k_pos(
    const float* __restrict__ embn, const float* __restrict__ a2,
    const int* __restrict__ clist, const int* __restrict__ coff,
    const int* __restrict__ ccount, float* __restrict__ dpos,
    float* __restrict__ dvalid) {
    const int c = blockIdx.y;
    const int m = ccount[c];
    const int it0 = blockIdx.x * TI;
    if (m == 0 || it0 >= m) return;  // block-uniform
    const int off = coff[c];
    const int tid = threadIdx.x;
    const int tx = tid & 31;
    const int ty = tid >> 5;
    const int lane = tid & 63;
    const int wav = tid >> 6;
    const int srow = tid >> 3;   // staging row (0..31)
    const int sslot = tid & 7;   // staging slot (0..7)

    __shared__ float4 At[8][TI];    // [slot][row], 4 KB
    __shared__ float4 Bt[8][TJ];    // [slot][row], 16 KB
    __shared__ int ig_s[TI];
    __shared__ float a2i_s[TI];
    __shared__ int jg_s[TJ];
    __shared__ float a2j_s[TJ];
    __shared__ int topj_s[TI][3];

    if (tid < TI) {
        const int gr = it0 + tid;
        const int gi = (gr < m) ? clist[off + gr] : -1;
        ig_s[tid] = gi;
        a2i_s[tid] = (gi >= 0) ? a2[gi] : 0.f;
    }

    float rv0[4], rv1[4], rv2[4];
    int rj0[4], rj1[4], rj2[4];
#pragma unroll
    for (int u = 0; u < 4; ++u) {
        rv0[u] = rv1[u] = rv2[u] = -FBIG;
        rj0[u] = rj1[u] = rj2[u] = -1;
    }

    for (int jb = 0; jb < m; jb += TJ) {
        __syncthreads();  // previous pass done with jg_s / LDS tiles; ig_s staged
        if (tid < TJ) {
            const int gr = jb + tid;
            const int gj = (gr < m) ? clist[off + gr] : -1;
            jg_s[tid] = gj;
            a2j_s[tid] = (gj >= 0) ? a2[gj] : 0.f;
        }
        __syncthreads();  // metadata ready

        // loop-invariant row pointers (dummy row 0 for padding; results unused)
        const int agi = ig_s[srow];
        const float4* gA = (const float4*)(embn + (size_t)((agi >= 0) ? agi : 0) * D);
        const int bg0 = jg_s[srow], bg1 = jg_s[32 + srow],
                  bg2 = jg_s[64 + srow], bg3 = jg_s[96 + srow];
        const float4* gB0 = (const float4*)(embn + (size_t)((bg0 >= 0) ? bg0 : 0) * D);
        const float4* gB1 = (const float4*)(embn + (size_t)((bg1 >= 0) ? bg1 : 0) * D);
        const float4* gB2 = (const float4*)(embn + (size_t)((bg2 >= 0) ? bg2 : 0) * D);
        const float4* gB3 = (const float4*)(embn + (size_t)((bg3 >= 0) ? bg3 : 0) * D);

        float acc[4][4];
#pragma unroll
        for (int u = 0; u < 4; ++u)
#pragma unroll
            for (int v = 0; v < 4; ++v) acc[u][v] = 0.f;

        // prefetch chunk 0
        float4 pa = gA[sslot];
        float4 pb0 = gB0[sslot], pb1 = gB1[sslot], pb2 = gB2[sslot], pb3 = gB3[sslot];

        for (int t = 0; t < 16; ++t) {
            __syncthreads();  // previous chunk's compute done; LDS free
            At[sslot][srow] = pa;
            Bt[sslot][srow] = pb0;
            Bt[sslot][32 + srow] = pb1;
            Bt[sslot][64 + srow] = pb2;
            Bt[sslot][96 + srow] = pb3;
            if (t < 15) {  // issue next chunk's loads (latency hides under compute)
                const int k4n = (t + 1) * 8 + sslot;
                pa = gA[k4n];
                pb0 = gB0[k4n]; pb1 = gB1[k4n]; pb2 = gB2[k4n]; pb3 = gB3[k4n];
            }
            __syncthreads();  // tile ready
#pragma unroll
            for (int k4 = 0; k4 < 8; ++k4) {
                const float4 b0 = Bt[k4][tx];
                const float4 b1 = Bt[k4][tx + 32];
                const float4 b2 = Bt[k4][tx + 64];
                const float4 b3 = Bt[k4][tx + 96];
#pragma unroll
                for (int u = 0; u < 4; ++u) {
                    const float4 a = At[k4][ty + 8 * u];  // broadcast
                    acc[u][0] += dot4(a, b0);
                    acc[u][1] += dot4(a, b1);
                    acc[u][2] += dot4(a, b2);
                    acc[u][3] += dot4(a, b3);
                }
            }
        }
        // selection: per-thread running top3 per owned i-row
#pragma unroll
        for (int u = 0; u < 4; ++u) {
            const int iloc = ty + 8 * u;
            const int ig = ig_s[iloc];
            if (ig < 0) continue;
            const float a2i = a2i_s[iloc];
#pragma unroll
            for (int v = 0; v < 4; ++v) {
                const int jloc = tx + 32 * v;
                const int jg = jg_s[jloc];
                if (jg >= 0 && jg != ig) {
                    const float sq = a2i + a2j_s[jloc] - 2.f * acc[u][v];
                    ins3(sq, jg, rv0[u], rv1[u], rv2[u], rj0[u], rj1[u], rj2[u]);
                }
            }
        }
    }

    // butterfly merge across the 32 tx lanes (stays within half-wave)
#pragma unroll
    for (int o = 16; o > 0; o >>= 1) {
#pragma unroll
        for (int u = 0; u < 4; ++u) {
            const float ov0 = __shfl_xor(rv0[u], o); const int oj0 = __shfl_xor(rj0[u], o);
            const float ov1 = __shfl_xor(rv1[u], o); const int oj1 = __shfl_xor(rj1[u], o);
            const float ov2 = __shfl_xor(rv2[u], o); const int oj2 = __shfl_xor(rj2[u], o);
            ins3(ov0, oj0, rv0[u], rv1[u], rv2[u], rj0[u], rj1[u], rj2[u]);
            ins3(ov1, oj1, rv0[u], rv1[u], rv2[u], rj0[u], rj1[u], rj2[u]);
            ins3(ov2, oj2, rv0[u], rv1[u], rv2[u], rj0[u], rj1[u], rj2[u]);
        }
    }
    if (tx == 0) {
#pragma unroll
        for (int u = 0; u < 4; ++u) {
            const int iloc = ty + 8 * u;
            topj_s[iloc][0] = rj0[u]; topj_s[iloc][1] = rj1[u]; topj_s[iloc][2] = rj2[u];
        }
    }
    __syncthreads();

    // d_pos tail: 4 waves round-robin the 32 rows
    for (int rl = wav; rl < TI; rl += 4) {
        if (it0 + rl >= m) continue;
        const int i = ig_s[rl];
        const int j0 = topj_s[rl][0], j1 = topj_s[rl][1], j2 = topj_s[rl][2];
        const int nw = (j0 >= 0) + (j1 >= 0) + (j2 >= 0);
        if (nw > 0) {
            const int jA = j0;
            const int jB = (j1 >= 0) ? j1 : jA;
            const int jC = (j2 >= 0) ? j2 : jB;
            const float4* pi = (const float4*)(embn + (size_t)i * D);
            const float4* r0 = (const float4*)(embn + (size_t)jA * D);
            const float4* r1 = (const float4*)(embn + (size_t)jB * D);
            const float4* r2 = (const float4*)(embn + (size_t)jC * D);
            float accp = 0.f;
#pragma unroll
            for (int s = 0; s < 2; ++s) {
                const int k4 = lane + 64 * s;
                const float4 a = pi[k4];
                const float4 v0 = r0[k4], v1 = r1[k4], v2 = r2[k4];
                const float cx = (v0.x + v1.x + v2.x) * (1.f / 3.f);
                const float cy = (v0.y + v1.y + v2.y) * (1.f / 3.f);
                const float cz = (v0.z + v1.z + v2.z) * (1.f / 3.f);
                const float cw = (v0.w + v1.w + v2.w) * (1.f / 3.f);
                const float dx = a.x - cx, dy = a.y - cy, dz = a.z - cz, dw = a.w - cw;
                accp += dx * dx + dy * dy + dz * dz + dw * dw;
            }
            accp = wave_rsum_all(accp);
            if (lane == 0) { dpos[i] = sqrtf(fmaxf(accp, FEPS)); dvalid[i] = 1.f; }
        } else if (lane == 0) {
            dpos[i] = 0.f; dvalid[i] = 0.f;
        }
    }
}

// --- 6. stable softplus + masked mean + last-block final division ---
__global__ void k_loss(const float* __restrict__ dpos, const float* __restrict__ dneg,
                       const float* __restrict__ dvalid, float* __restrict__ accum,
                       int* __restrict__ done, float* __restrict__ out,
                       int n, int nblocks) {
    const int i = blockIdx.x * blockDim.x + threadIdx.x;
    float l = 0.f, v = 0.f;
    if (i < n) {
        v = dvalid[i];
        const float x = dpos[i] - dneg[i];
        const float sp = fmaxf(x, 0.f) + log1pf(expf(-fabsf(x)));
        l = sp * v;
    }
    l = wave_rsum(l);
    v = wave_rsum(v);
    __shared__ float wl[4], wv[4];
    const int lane = threadIdx.x & 63, w = threadIdx.x >> 6;
    if (lane == 0) { wl[w] = l; wv[w] = v; }
    __syncthreads();
    if (threadIdx.x == 0) {
        atomicAdd(&accum[0], wl[0] + wl[1] + wl[2] + wl[3]);
        atomicAdd(&accum[1], wv[0] + wv[1] + wv[2] + wv[3]);
        __threadfence();
        const int prev = atomicAdd(done, 1);
        if (prev == nblocks - 1) {
            __threadfence();
            const float sl = atomicAdd(&accum[0], 0.0f);  // coherent-point read
            const float sv = atomicAdd(&accum[1], 0.0f);
            out[0] = sl / fmaxf(sv, 1.0f);
        }
    }
}

extern "C" void kernel_launch(void* const* d_in, const int* in_sizes, int n_in,
                              void* d_out, int out_size, void* d_ws, size_t ws_size,
                              hipStream_t stream) {
    const float* emb = (const float*)d_in[0];
    const int* targets = (const int*)d_in[1];
    const int* ncls = (const int*)d_in[2];
    const int n = in_sizes[1];  // 8192

    float* fp = (float*)d_ws;
    float* embn = fp;    fp += (size_t)n * D;
    float* a2 = fp;      fp += n;
    float* centers = fp; fp += (size_t)MAXC * D;
    float* dneg = fp;    fp += n;
    float* dpos = fp;    fp += n;
    float* dvalid = fp;  fp += n;
    int* ccount = (int*)fp; fp += MAXC;
    float* accum = fp;   fp += 2;          // contiguous with ccount: one memset
    int* done = (int*)fp; fp += 1;
    int* coff = (int*)fp;   fp += MAXC;
    int* clist = (int*)fp;  fp += n;

    hipMemsetAsync(ccount, 0, (MAXC + 3) * sizeof(int), stream);

    const int nloss = (n + 255) / 256;
    k_normalize<<<n, 128, 0, stream>>>(emb, targets, embn, a2, ccount);
    k_build<<<MAXC, 256, 0, stream>>>(targets, ccount, coff, clist, n, ncls);
    k_centers<<<dim3(4, MAXC), 128, 0, stream>>>(embn, clist, coff, ccount, centers);
    k_dneg<<<(n + DROWS - 1) / DROWS, 128, 0, stream>>>(embn, a2, targets, centers, dneg, n, ncls);
    k_pos<<<dim3(NIT, MAXC), 256, 0, stream>>>(embn, a2, clist, coff, ccount, dpos, dvalid);
    k_loss<<<nloss, 256, 0, stream>>>(dpos, dneg, dvalid, accum, done, (float*)d_out, n, nloss);
}